// Round 9
// baseline (44.983 us; speedup 1.0000x reference)
//
#include <hip/hip_runtime.h>
#include <hip/hip_bf16.h>

#define BB 16
#define FF 128
#define HH 144
#define EE 24
#define C0C 12

typedef float v4f __attribute__((ext_vector_type(4)));

__device__ __forceinline__ float fastdiv(float n, float d) {
    float r = __builtin_amdgcn_rcpf(d);
    r = fmaf(fmaf(-d, r, 1.0f), r, r);   // one Newton iteration
    return n * r;
}

// Fully fused: one block = (b, 16-wide h-slice, group of 4 s-pairs).
// Block recomputes the (num,den) prefix tables for its h-slice in LDS
// (redundant across s-groups: ~100 kFLOP/block, ~1.5 us device-wide,
// hidden under the store stream), then streams its output slabs.
// Grid 2304 = 8 xcd * 288; b = 2*(blk&7)+(v>=144) pins each b to one XCD.
__global__ __launch_bounds__(256) void seg_fused(
    const float* __restrict__ note,   // [B][F][E]
    const float* __restrict__ hv,     // [B][H][E]
    const float* __restrict__ W0,     // [12][12]
    const float* __restrict__ b0,     // [12]
    const float* __restrict__ W1,     // [12][12]
    const float* __restrict__ b1,     // [12]
    const float* __restrict__ Wc,     // [24][24]
    const float* __restrict__ bc,     // [24]
    float* __restrict__ out)          // [B][F(s)][F(e)][H]
{
    const int blk = blockIdx.x;
    const int x = blk & 7;             // XCD
    const int v = blk >> 3;            // 0..287
    const int b = 2 * x + (v >= 144);
    const int w = (v >= 144) ? v - 144 : v;   // 0..143
    const int hs = w >> 4;             // 0..8  h-slice
    const int sg = w & 15;             // 0..15 s-pair group (4 pairs)
    const int h0 = hs * 16;
    const int tid = threadIdx.x;

    __shared__ float s_hcat[16][EE];   // 1.5 KB
    __shared__ float s_q[16][EE];      // 1.5 KB
    __shared__ float s_num[FF + 1][16];// 8.25 KB  cumsum(p*d), row 0 = 0
    __shared__ float s_den[FF + 1][16];// 8.25 KB  cumsum(p),   row 0 = 0
    __shared__ float s_pm[16][16];     // 1 KB
    __shared__ float s_m[16];

    // ---- q for the 16 harmonies of this slice ----
    for (int idx = tid; idx < 16 * EE; idx += 256) {
        const int hl = idx / EE, e = idx - hl * EE;
        const float* hvb = hv + ((size_t)b * HH + h0 + hl) * EE;
        float acc;
        if (e < C0C) {
            acc = b0[e];
            #pragma unroll
            for (int j = 0; j < C0C; ++j) acc += W0[e * C0C + j] * hvb[j];
        } else {
            const int e1 = e - C0C;
            acc = b1[e1];
            #pragma unroll
            for (int j = 0; j < C0C; ++j) acc += W1[e1 * C0C + j] * hvb[C0C + j];
        }
        s_hcat[hl][e] = acc;
    }
    __syncthreads();
    for (int idx = tid; idx < 16 * EE; idx += 256) {
        const int hl = idx / EE, e = idx - hl * EE;
        float acc = bc[e];
        #pragma unroll
        for (int j = 0; j < EE; ++j) acc += Wc[e * EE + j] * s_hcat[hl][j];
        s_q[hl][e] = acc;
    }
    if (tid < 16) {
        s_num[0][tid] = 0.f;
        s_den[0][tid] = 0.f;
    }
    __syncthreads();

    // ---- d, softmax terms; thread = (hl = tid&15, f0 = tid>>4), 8 f each ----
    const int hl = tid & 15;
    const int f0 = tid >> 4;
    const float scale = 0.20412414523193150818f;  // 1/sqrt(24)
    const float* nb_ = note + (size_t)b * FF * EE;

    float dv[8];
    float pmax = -3.4e38f;
    #pragma unroll
    for (int k = 0; k < 8; ++k) {
        const int f = f0 + (k << 4);
        const float* nr = nb_ + f * EE;
        float acc = 0.f;
        #pragma unroll
        for (int e = 0; e < EE; e += 4) {
            const v4f nv = *reinterpret_cast<const v4f*>(nr + e);
            acc += s_q[hl][e] * nv.x + s_q[hl][e + 1] * nv.y
                 + s_q[hl][e + 2] * nv.z + s_q[hl][e + 3] * nv.w;
        }
        dv[k] = acc;
        pmax = fmaxf(pmax, acc);
    }
    s_pm[f0][hl] = pmax * scale;
    __syncthreads();
    if (tid < 16) {
        float m = s_pm[0][tid];
        #pragma unroll
        for (int r = 1; r < 16; ++r) m = fmaxf(m, s_pm[r][tid]);
        s_m[tid] = m;
    }
    __syncthreads();
    const float m = s_m[hl];

    #pragma unroll
    for (int k = 0; k < 8; ++k) {
        const int f = f0 + (k << 4);
        const float p = __expf(dv[k] * scale - m);
        s_num[f + 1][hl] = p * dv[k];
        s_den[f + 1][hl] = p;
    }
    __syncthreads();

    // ---- Hillis-Steele inclusive scan over f (16 cols in parallel) ----
    for (int off = 1; off < FF; off <<= 1) {
        float tp[8], tpd[8];
        #pragma unroll
        for (int k = 0; k < 8; ++k) {
            const int f = f0 + (k << 4);
            tp[k] = (f >= off) ? s_num[f + 1 - off][hl] : 0.f;
            tpd[k] = (f >= off) ? s_den[f + 1 - off][hl] : 0.f;
        }
        __syncthreads();
        #pragma unroll
        for (int k = 0; k < 8; ++k) {
            const int f = f0 + (k << 4);
            if (f >= off) { s_num[f + 1][hl] += tp[k]; s_den[f + 1][hl] += tpd[k]; }
        }
        __syncthreads();
    }

    // ---- output: 8 slabs (4 complementary s-pairs), 16-h slice ----
    // thread -> (erow = tid>>2, q4 = (tid&3)*4); e in {erow, erow+64}
    const int q4 = (tid & 3) * 4;
    const int er = tid >> 2;
    float* out_b = out + (size_t)b * (FF * FF * HH) + h0;

    #pragma unroll
    for (int pp = 0; pp < 4; ++pp) {
        const int s_lo = sg * 4 + pp;          // 0..63
        #pragma unroll
        for (int side = 0; side < 2; ++side) {
            const int s = side ? 127 - s_lo : s_lo;
            float* ob = out_b + (size_t)s * (FF * HH);
            const v4f n0 = *reinterpret_cast<const v4f*>(&s_num[s][q4]);
            const v4f d0 = *reinterpret_cast<const v4f*>(&s_den[s][q4]);
            int e = er;
            #pragma unroll
            for (int k = 0; k < 2; ++k, e += 64) {
                v4f val = (v4f)(0.f);
                if (e >= s) {
                    const v4f n1 = *reinterpret_cast<const v4f*>(&s_num[e + 1][q4]);
                    const v4f d1 = *reinterpret_cast<const v4f*>(&s_den[e + 1][q4]);
                    val.x = fastdiv(n1.x - n0.x, d1.x - d0.x);
                    val.y = fastdiv(n1.y - n0.y, d1.y - d0.y);
                    val.z = fastdiv(n1.z - n0.z, d1.z - d0.z);
                    val.w = fastdiv(n1.w - n0.w, d1.w - d0.w);
                }
                *reinterpret_cast<v4f*>(ob + (size_t)e * HH + q4) = val;
            }
        }
    }
}

extern "C" void kernel_launch(void* const* d_in, const int* in_sizes, int n_in,
                              void* d_out, int out_size, void* d_ws, size_t ws_size,
                              hipStream_t stream) {
    const float* note = (const float*)d_in[0];
    const float* hv   = (const float*)d_in[1];
    const float* W0   = (const float*)d_in[2];
    const float* b0   = (const float*)d_in[3];
    const float* W1   = (const float*)d_in[4];
    const float* b1   = (const float*)d_in[5];
    const float* Wc   = (const float*)d_in[6];
    const float* bc   = (const float*)d_in[7];
    float* out = (float*)d_out;

    seg_fused<<<2304, 256, 0, stream>>>(note, hv, W0, b0, W1, b1, Wc, bc, out);
}

// Round 10
// 34.178 us; speedup vs baseline: 1.3161x; 1.3161x over previous
//
#include <hip/hip_runtime.h>
#include <hip/hip_bf16.h>

#define BB 16
#define FF 128
#define HH 144
#define EE 24
#define C0C 12

typedef float v4f __attribute__((ext_vector_type(4)));

// Workspace layout (floats), h-minor so K2 reads are lane-coalesced:
//   num_t: [B][F+1][H]  (cumsum of p*d, leading zero row)
//   den_t: [B][F+1][H]  (cumsum of p,   leading zero row)
#define TABLE_ELEMS (BB * (FF + 1) * HH)

__device__ __forceinline__ float fastdiv(float n, float d) {
    float r = __builtin_amdgcn_rcpf(d);
    r = fmaf(fmaf(-d, r, 1.0f), r, r);   // one Newton iteration
    return n * r;
}

// Kernel A: blocks 0..143 compute the prefix tables (one block per
// (b, 16-wide h-tile)); blocks 144..1167 zero-fill the e<s triangle
// (contiguous slab-prefix runs). Table blocks are first in the grid so
// they dispatch first; zero stores keep the other CUs saturated, hiding
// the table compute + its scan barriers entirely.
__global__ __launch_bounds__(256) void seg_pre(
    const float* __restrict__ note,   // [B][F][E]
    const float* __restrict__ hv,     // [B][H][E]
    const float* __restrict__ W0,     // [12][12]
    const float* __restrict__ b0,     // [12]
    const float* __restrict__ W1,     // [12][12]
    const float* __restrict__ b1,     // [12]
    const float* __restrict__ Wc,     // [24][24]
    const float* __restrict__ bc,     // [24]
    float* __restrict__ num_t,
    float* __restrict__ den_t,
    float* __restrict__ out)          // [B][F(s)][F(e)][H]
{
    const int blk = blockIdx.x;
    const int tid = threadIdx.x;

    __shared__ float s_note[FF * EE];  // 12 KB
    __shared__ float s_hcat[16][EE];
    __shared__ float s_q[16][EE];
    __shared__ float s_p[FF][16];      // 8 KB
    __shared__ float s_pd[FF][16];     // 8 KB
    __shared__ float s_pm[16][16];
    __shared__ float s_m[16];

    if (blk >= 144) {
        // ---- zero-fill blocks: pair (sp, 127-sp) of batch b ----
        const int z = blk - 144;       // 0..1023
        const int x = z & 7;
        const int t = z >> 3;          // 0..127
        const int b = 2 * x + (t >= 64);
        const int sp = (t >= 64) ? t - 64 : t;   // 0..63
        float* out_b = out + (size_t)b * (FF * FF * HH);

        // slab sp: rows [0, sp) contiguous; slab 127-sp: rows [0, 127-sp)
        v4f* r1 = reinterpret_cast<v4f*>(out_b + (size_t)sp * FF * HH);
        const int n1 = sp * (HH / 4);
        for (int c = tid; c < n1; c += 256) r1[c] = (v4f)(0.f);

        v4f* r2 = reinterpret_cast<v4f*>(out_b + (size_t)(127 - sp) * FF * HH);
        const int n2 = (127 - sp) * (HH / 4);
        for (int c = tid; c < n2; c += 256) r2[c] = (v4f)(0.f);
        return;
    }

    // ---- table blocks: one per (b, 16-h tile) ----
    const int x = blk & 7;
    const int t = blk >> 3;            // 0..17
    const int b = 2 * x + (t >= 9);
    const int tile = (t >= 9) ? t - 9 : t;   // 0..8
    const int h0 = tile * 16;

    // stage note[b] coalesced (768 v4f / 256 thr = 3 each)
    const float* nb_ = note + (size_t)b * FF * EE;
    for (int k = tid; k < FF * EE / 4; k += 256)
        reinterpret_cast<v4f*>(s_note)[k] = reinterpret_cast<const v4f*>(nb_)[k];

    // hcat for the 16 harmonies of this tile
    for (int idx = tid; idx < 16 * EE; idx += 256) {
        const int hl = idx / EE, e = idx - hl * EE;
        const float* hvb = hv + ((size_t)b * HH + h0 + hl) * EE;
        float acc;
        if (e < C0C) {
            acc = b0[e];
            #pragma unroll
            for (int j = 0; j < C0C; ++j) acc += W0[e * C0C + j] * hvb[j];
        } else {
            const int e1 = e - C0C;
            acc = b1[e1];
            #pragma unroll
            for (int j = 0; j < C0C; ++j) acc += W1[e1 * C0C + j] * hvb[C0C + j];
        }
        s_hcat[hl][e] = acc;
    }
    __syncthreads();
    for (int idx = tid; idx < 16 * EE; idx += 256) {
        const int hl = idx / EE, e = idx - hl * EE;
        float acc = bc[e];
        #pragma unroll
        for (int j = 0; j < EE; ++j) acc += Wc[e * EE + j] * s_hcat[hl][j];
        s_q[hl][e] = acc;
    }
    __syncthreads();

    // d for 8 f's per thread; thread = (hl = tid&15, f0 = tid>>4)
    const int hl = tid & 15;
    const int f0 = tid >> 4;
    const float scale = 0.20412414523193150818f;  // 1/sqrt(24)

    float dv[8];
    float pmax = -3.4e38f;
    #pragma unroll
    for (int k = 0; k < 8; ++k) {
        const int f = f0 + (k << 4);
        float acc = 0.f;
        #pragma unroll
        for (int e = 0; e < EE; ++e) acc += s_q[hl][e] * s_note[f * EE + e];
        dv[k] = acc;
        pmax = fmaxf(pmax, acc);
    }
    s_pm[f0][hl] = pmax * scale;   // column-partial max of d*scale (scale > 0)
    __syncthreads();
    if (tid < 16) {
        float m = s_pm[0][tid];
        #pragma unroll
        for (int r = 1; r < 16; ++r) m = fmaxf(m, s_pm[r][tid]);
        s_m[tid] = m;
    }
    __syncthreads();
    const float m = s_m[hl];

    #pragma unroll
    for (int k = 0; k < 8; ++k) {
        const int f = f0 + (k << 4);
        const float p = __expf(dv[k] * scale - m);
        s_p[f][hl] = p;
        s_pd[f][hl] = p * dv[k];
    }
    __syncthreads();

    // Hillis-Steele inclusive scan over f (16 columns in parallel)
    for (int off = 1; off < FF; off <<= 1) {
        float tp[8], tpd[8];
        #pragma unroll
        for (int k = 0; k < 8; ++k) {
            const int f = f0 + (k << 4);
            tp[k] = (f >= off) ? s_p[f - off][hl] : 0.f;
            tpd[k] = (f >= off) ? s_pd[f - off][hl] : 0.f;
        }
        __syncthreads();
        #pragma unroll
        for (int k = 0; k < 8; ++k) {
            const int f = f0 + (k << 4);
            if (f >= off) { s_p[f][hl] += tp[k]; s_pd[f][hl] += tpd[k]; }
        }
        __syncthreads();
    }

    // write tables: full 64B segments per f-row
    const size_t base = (size_t)b * (FF + 1) * HH + h0;
    for (int idx4 = tid; idx4 < 512; idx4 += 256) {
        const int f = idx4 >> 2;           // 0..127
        const int hh = (idx4 & 3) * 4;     // 0,4,8,12
        *reinterpret_cast<v4f*>(num_t + base + (size_t)(f + 1) * HH + hh) =
            *reinterpret_cast<const v4f*>(&s_pd[f][hh]);
        *reinterpret_cast<v4f*>(den_t + base + (size_t)(f + 1) * HH + hh) =
            *reinterpret_cast<const v4f*>(&s_p[f][hh]);
    }
    if (tid < 16) {
        num_t[base + tid] = 0.f;
        den_t[base + tid] = 0.f;
    }
}

// Kernel B: compute triangle only (e >= s), zeros already written.
//   compute rows: e = s + r + 7*half + 14k  (r = tid/36)
__device__ __forceinline__ void k2_row_half(
    const float* __restrict__ nb, const float* __restrict__ db,
    float* __restrict__ out_b, int s, int tid, int half)
{
    float* ob = out_b + (size_t)s * (FF * HH);

    if (tid < 252) {
        const int r = tid / 36;                   // 0..6
        const int hq = tid - r * 36;              // 0..35
        const int h = hq * 4;

        const v4f n0 = *reinterpret_cast<const v4f*>(nb + (size_t)s * HH + h);
        const v4f d0 = *reinterpret_cast<const v4f*>(db + (size_t)s * HH + h);

        const int e0 = s + r + 7 * half;
        const float* pn = nb + (size_t)(e0 + 1) * HH + h;
        const float* pd_ = db + (size_t)(e0 + 1) * HH + h;
        float* po = ob + (size_t)e0 * HH + h;

        #pragma unroll 2
        for (int e = e0; e < FF; e += 14) {
            const v4f n1 = *reinterpret_cast<const v4f*>(pn);
            const v4f d1 = *reinterpret_cast<const v4f*>(pd_);
            v4f val;
            val.x = fastdiv(n1.x - n0.x, d1.x - d0.x);
            val.y = fastdiv(n1.y - n0.y, d1.y - d0.y);
            val.z = fastdiv(n1.z - n0.z, d1.z - d0.z);
            val.w = fastdiv(n1.w - n0.w, d1.w - d0.w);
            *reinterpret_cast<v4f*>(po) = val;
            pn += 14 * HH;
            pd_ += 14 * HH;
            po += 14 * HH;
        }
    }
}

__global__ __launch_bounds__(256) void seg_k2(
    const float* __restrict__ num_t,
    const float* __restrict__ den_t,
    float* __restrict__ out)          // [B][F(s)][F(e)][H]
{
    // XCD swizzle: xcd = blk&7 owns b in {2*xcd, 2*xcd+1} -> table slice
    // (0.74 MB) stays resident in that XCD's 4 MB L2.
    const int blk = blockIdx.x;        // 2048
    const int x = blk & 7;
    const int t = blk >> 3;            // 0..255
    const int b = 2 * x + (t >= 128);
    const int j = t & 127;
    const int sp = j >> 1;             // 0..63
    const int half = j & 1;
    const int tid = threadIdx.x;

    const float* nb = num_t + (size_t)b * (FF + 1) * HH;
    const float* db = den_t + (size_t)b * (FF + 1) * HH;
    float* out_b = out + (size_t)b * (FF * FF * HH);

    // paired s values: constant compute-row count per block
    k2_row_half(nb, db, out_b, sp, tid, half);
    k2_row_half(nb, db, out_b, 127 - sp, tid, half);
}

extern "C" void kernel_launch(void* const* d_in, const int* in_sizes, int n_in,
                              void* d_out, int out_size, void* d_ws, size_t ws_size,
                              hipStream_t stream) {
    const float* note = (const float*)d_in[0];
    const float* hv   = (const float*)d_in[1];
    const float* W0   = (const float*)d_in[2];
    const float* b0   = (const float*)d_in[3];
    const float* W1   = (const float*)d_in[4];
    const float* b1   = (const float*)d_in[5];
    const float* Wc   = (const float*)d_in[6];
    const float* bc   = (const float*)d_in[7];
    float* out = (float*)d_out;

    float* num_t = (float*)d_ws;
    float* den_t = num_t + TABLE_ELEMS;

    seg_pre<<<144 + 1024, 256, 0, stream>>>(note, hv, W0, b0, W1, b1, Wc, bc,
                                            num_t, den_t, out);
    seg_k2<<<BB * FF, 256, 0, stream>>>(num_t, den_t, out);
}